// Round 5
// baseline (136.113 us; speedup 1.0000x reference)
//
#include <hip/hip_runtime.h>

// ShuffleNet unit, fp32, NCHW. B=64, Cin=Cout=480, mid=120, H=W=28.
// K1: ic-split across wave pairs + LDS reduce -> read-once AND 18 waves/CU.
// K2: depthwise 3x3, shuffle folded into write. K3: wave-per-oc-chunk conv3.

namespace {
constexpr int CIN = 480;
constexpr int MID = 120;
constexpr int HWP = 784;
constexpr float EPSV = 1e-5f;
}

// ---------- K1: 1x1 grouped conv (480->120, G=3) + BN + ReLU ----------
// block: 256 thr = 4 waves. px tile 128. wave pair (ich=0,1) splits ic 160=2x80.
// each thread: 1 px, 40 oc, 80 ic. LDS reduce. grid (392, 3)
__global__ __launch_bounds__(256) void k1_conv1(
    const float* __restrict__ x,  const float* __restrict__ w1,
    const float* __restrict__ g1, const float* __restrict__ b1,
    const float* __restrict__ m1, const float* __restrict__ v1,
    float* __restrict__ tmp1)
{
    __shared__ float red[128][41];                        // padded: conflict-free

    const int tid  = threadIdx.x;
    const int lane = tid & 63;
    const int wv   = tid >> 6;                            // 0..3
    int ich = wv & 1;                                     // ic half
    ich = __builtin_amdgcn_readfirstlane(ich);            // force SGPR weight path
    const int pxl  = lane + ((wv >> 1) << 6);             // 0..127
    const int p    = blockIdx.x * 128 + pxl;              // global px
    const int b    = p / HWP;
    const int hw   = p - b * HWP;
    const int g    = blockIdx.y;

    const float* __restrict__ xp = x + (size_t)(b * CIN + g * 160 + ich * 80) * HWP + hw;
    const float* __restrict__ wp = w1 + g * 40 * 160 + ich * 80;

    float acc[40];
#pragma unroll
    for (int j = 0; j < 40; ++j) acc[j] = 0.f;

#pragma unroll 4
    for (int ic = 0; ic < 80; ++ic) {
        const float xv = xp[(size_t)ic * HWP];
#pragma unroll
        for (int j = 0; j < 40; ++j)
            acc[j] = fmaf(xv, wp[j * 160 + ic], acc[j]); // weight: SGPR load
    }

    if (ich == 1) {
#pragma unroll
        for (int j = 0; j < 40; ++j) red[pxl][j] = acc[j];
    }
    __syncthreads();
    if (ich == 0) {
        const int oc0 = g * 40;
        float* __restrict__ op = tmp1 + (size_t)(b * MID + oc0) * HWP + hw;
#pragma unroll
        for (int j = 0; j < 40; ++j) {
            const int oc = oc0 + j;
            const float s  = g1[oc] * rsqrtf(v1[oc] + EPSV);
            const float sh = fmaf(-m1[oc], s, b1[oc]);
            float v = fmaf(acc[j] + red[pxl][j], s, sh);
            op[(size_t)j * HWP] = v > 0.f ? v : 0.f;
        }
    }
}

// ---------- K2: depthwise 3x3 + BN, shuffle folded into write ----------
// thread: 4 adjacent px (same row), 1 channel. grid (49, 120)
__global__ __launch_bounds__(256) void k2_dw(
    const float* __restrict__ tmp1, const float* __restrict__ w2,
    const float* __restrict__ g2,   const float* __restrict__ b2,
    const float* __restrict__ m2,   const float* __restrict__ v2,
    float* __restrict__ tmp2)
{
    const int t  = blockIdx.x * 256 + threadIdx.x;        // 0..12543
    const int b  = t / 196;
    const int hw = (t - b * 196) * 4;
    const int h  = hw / 28;
    const int w  = hw - h * 28;                           // 0,4,...,24
    const int c  = blockIdx.y;                            // uniform
    const float* __restrict__ in = tmp1 + (size_t)(b * MID + c) * HWP;

    float wk[9];
#pragma unroll
    for (int i = 0; i < 9; ++i) wk[i] = w2[c * 9 + i];    // SGPR loads

    float a0 = 0.f, a1 = 0.f, a2 = 0.f, a3 = 0.f;
#pragma unroll
    for (int dh = -1; dh <= 1; ++dh) {
        const int hh = h + dh;
        if (hh < 0 || hh > 27) continue;
        const float* r = in + hh * 28 + w;
        const float4 c4 = *reinterpret_cast<const float4*>(r);
        const float cl = (w > 0)  ? r[-1] : 0.f;
        const float cr = (w < 24) ? r[4]  : 0.f;
        const float* wr = wk + (dh + 1) * 3;
        a0 = fmaf(cl,   wr[0], a0); a0 = fmaf(c4.x, wr[1], a0); a0 = fmaf(c4.y, wr[2], a0);
        a1 = fmaf(c4.x, wr[0], a1); a1 = fmaf(c4.y, wr[1], a1); a1 = fmaf(c4.z, wr[2], a1);
        a2 = fmaf(c4.y, wr[0], a2); a2 = fmaf(c4.z, wr[1], a2); a2 = fmaf(c4.w, wr[2], a2);
        a3 = fmaf(c4.z, wr[0], a3); a3 = fmaf(c4.w, wr[1], a3); a3 = fmaf(cr,   wr[2], a3);
    }
    const float s  = g2[c] * rsqrtf(v2[c] + EPSV);
    const float sh = fmaf(-m2[c], s, b2[c]);
    const int gi = c / 40;
    const int cs = (c - gi * 40) * 3 + gi;                // channel shuffle
    float4 o;
    o.x = fmaf(a0, s, sh); o.y = fmaf(a1, s, sh);
    o.z = fmaf(a2, s, sh); o.w = fmaf(a3, s, sh);
    *reinterpret_cast<float4*>(tmp2 + (size_t)(b * MID + cs) * HWP + hw) = o;
}

// ---------- K3: 1x1 grouped conv (120->480) + BN + ReLU + shortcut ----------
// block: 256 thr = 4 waves, 128 px tile; wave w -> oc [g*160+w*40, +40).
// grid (392, 3)
__global__ __launch_bounds__(256) void k3_conv3(
    const float* __restrict__ tmp2, const float* __restrict__ w3,
    const float* __restrict__ g3,   const float* __restrict__ b3,
    const float* __restrict__ m3,   const float* __restrict__ v3,
    const float* __restrict__ x,    float* __restrict__ out)
{
    const int lane = threadIdx.x & 63;
    const int wv   = threadIdx.x >> 6;
    const int p    = blockIdx.x * 128 + lane * 2;         // global px pair
    const int b    = p / HWP;
    const int hw   = p - b * HWP;
    const int g    = blockIdx.y;
    int oc0 = g * 160 + wv * 40;
    oc0 = __builtin_amdgcn_readfirstlane(oc0);            // force SGPR weight path

    const float* __restrict__ ip = tmp2 + (size_t)(b * MID + g * 40) * HWP + hw;
    const float* __restrict__ wp = w3 + (size_t)oc0 * 40;

    float acc0[40], acc1[40];
#pragma unroll
    for (int j = 0; j < 40; ++j) { acc0[j] = 0.f; acc1[j] = 0.f; }

#pragma unroll 4
    for (int ic = 0; ic < 40; ++ic) {
        const float2 xv = *reinterpret_cast<const float2*>(ip + (size_t)ic * HWP);
#pragma unroll
        for (int j = 0; j < 40; ++j) {
            const float w = wp[j * 40 + ic];              // SGPR load
            acc0[j] = fmaf(xv.x, w, acc0[j]);
            acc1[j] = fmaf(xv.y, w, acc1[j]);
        }
    }

    const float* __restrict__ sp = x   + (size_t)(b * CIN + oc0) * HWP + hw;
    float*       __restrict__ op = out + (size_t)(b * CIN + oc0) * HWP + hw;
#pragma unroll
    for (int j = 0; j < 40; ++j) {
        const int oc = oc0 + j;
        const float s  = g3[oc] * rsqrtf(v3[oc] + EPSV);
        const float sh = fmaf(-m3[oc], s, b3[oc]);
        const float2 sc = *reinterpret_cast<const float2*>(sp + (size_t)j * HWP);
        float2 o;
        o.x = fmaf(acc0[j], s, sh); o.x = (o.x > 0.f ? o.x : 0.f) + sc.x;
        o.y = fmaf(acc1[j], s, sh); o.y = (o.y > 0.f ? o.y : 0.f) + sc.y;
        *reinterpret_cast<float2*>(op + (size_t)j * HWP) = o;
    }
}

extern "C" void kernel_launch(void* const* d_in, const int* in_sizes, int n_in,
                              void* d_out, int out_size, void* d_ws, size_t ws_size,
                              hipStream_t stream) {
    const float* x  = (const float*)d_in[0];
    const float* w1 = (const float*)d_in[1];
    const float* g1 = (const float*)d_in[2];
    const float* b1 = (const float*)d_in[3];
    const float* m1 = (const float*)d_in[4];
    const float* v1 = (const float*)d_in[5];
    const float* w2 = (const float*)d_in[6];
    const float* g2 = (const float*)d_in[7];
    const float* b2 = (const float*)d_in[8];
    const float* m2 = (const float*)d_in[9];
    const float* v2 = (const float*)d_in[10];
    const float* w3 = (const float*)d_in[11];
    const float* g3 = (const float*)d_in[12];
    const float* b3 = (const float*)d_in[13];
    const float* m3 = (const float*)d_in[14];
    const float* v3 = (const float*)d_in[15];
    float* out = (float*)d_out;

    float* tmp1 = (float*)d_ws;                           // 24.1 MB
    float* tmp2 = tmp1 + (size_t)64 * MID * HWP;          // 24.1 MB

    k1_conv1<<<dim3(392, 3), 256, 0, stream>>>(x, w1, g1, b1, m1, v1, tmp1);
    k2_dw   <<<dim3(49, 120), 256, 0, stream>>>(tmp1, w2, g2, b2, m2, v2, tmp2);
    k3_conv3<<<dim3(392, 3), 256, 0, stream>>>(tmp2, w3, g3, b3, m3, v3, x, out);
}